// Round 12
// baseline (386.013 us; speedup 1.0000x reference)
//
#include <hip/hip_runtime.h>
#include <math.h>

#define GSZ  96
#define GS2  (GSZ*GSZ)            // 9216
#define NPTS (GSZ*GSZ*GSZ)        // 884736
#define NVIEW 8
#define HIM  256
#define WIM  256

#define SCENE_SZ   (3*GS2)        // 27648
#define OUTLAT_OFF (3*SCENE_SZ)   // 82944
#define LAT5_OFF   (OUTLAT_OFF + NVIEW*3*NPTS)  // 82944 + 21233664

__device__ __forceinline__ float red_max64(float v) {
    #pragma unroll
    for (int m = 32; m >= 1; m >>= 1) v = fmaxf(v, __shfl_xor(v, m, 64));
    return v;
}
__device__ __forceinline__ float red_sum64(float v) {
    #pragma unroll
    for (int m = 32; m >= 1; m >>= 1) v += __shfl_xor(v, m, 64);
    return v;
}

// Kernel 1: per world point, loop 8 views: project -> bilinear sample -> tiny MLP.
// Writes out_latent [NV][3][NPTS], lat5 [NV][NPTS][3], latm [3][NPTS] (mean over views).
__global__ __launch_bounds__(256)
void k1_sample_mlp(const float* __restrict__ images, const float* __restrict__ poses,
                   const float* __restrict__ focal, const float* __restrict__ cc,
                   const float* __restrict__ dw1, const float* __restrict__ db1,
                   const float* __restrict__ dw2, const float* __restrict__ db2,
                   const float* __restrict__ dw3, const float* __restrict__ db3,
                   float* __restrict__ out_latent, float* __restrict__ lat5,
                   float* __restrict__ latm, int write_latm)
{
    const int p   = blockIdx.x * 256 + threadIdx.x;
    const int ix  = p / GS2;
    const int rem = p - ix * GS2;
    const int iy  = rem / GSZ;
    const int iz  = rem - iy * GSZ;
    // world grid: xs,ys = linspace(-1,1,96); zs = linspace(0,1,96)
    const float wxv = (float)ix * (2.0f/95.0f) - 1.0f;
    const float wyv = (float)iy * (2.0f/95.0f) - 1.0f;
    const float wzv = (float)iz * (1.0f/95.0f);

    const float f   = focal[0] * 0.5f;   // focal / stride, stride = 2
    const float c2x = cc[0] * 0.5f;
    const float c2y = cc[1] * 0.5f;

    float a0 = 0.f, a1 = 0.f, a2 = 0.f;   // latm accumulator (sum over views)

    for (int n = 0; n < NVIEW; ++n) {
        const float* ps = poses + n * 16;
        const float r00 = ps[0], r01 = ps[1], r02 = ps[2],  tx = ps[3];
        const float r10 = ps[4], r11 = ps[5], r12 = ps[6],  ty = ps[7];
        const float r20 = ps[8], r21 = ps[9], r22 = ps[10], tz = ps[11];

        const float dx = wxv - tx, dy = wyv - ty, dz = wzv - tz;
        // cam_i = sum_j d_j * R[j][i]
        const float camx = dx*r00 + dy*r10 + dz*r20;
        const float camy = dx*r01 + dy*r11 + dz*r21;
        const float camz = dx*r02 + dy*r12 + dz*r22;

        const float ex = dx + 1e-9f, ey = dy + 1e-9f, ez = dz + 1e-9f;
        const float dn = sqrtf(ex*ex + ey*ey + ez*ez);
        const bool  mz = camz < 0.001f;
        float d0 = 0.f, d1 = 0.f, d2 = 0.f;   // dirs * mask_z
        if (mz) { d0 = dx/dn; d1 = dy/dn; d2 = dz/dn; }

        const float u = camx/camz * f    + c2x;
        const float v = camy/camz * (-f) + c2y;
        const float gxn = 2.0f*u/127.0f - 1.0f;   // W_feat-1 = 127
        const float gyn = 2.0f*v/127.0f - 1.0f;

        float l0 = 0.f, l1 = 0.f, l2 = 0.f;
        const bool inside = (fabsf(gxn) <= 1.0f) && (fabsf(gyn) <= 1.0f) && mz;
        if (inside) {
            // grid_sample on full-res feats (H=W=256), zero-pad corners
            const float sx = (gxn + 1.0f) * 255.0f * 0.5f;
            const float sy = (gyn + 1.0f) * 255.0f * 0.5f;
            const float x0f = floorf(sx), y0f = floorf(sy);
            const float fx = sx - x0f, fy = sy - y0f;
            const int x0 = (int)x0f, y0 = (int)y0f;
            const int x1 = x0 + 1,  y1 = y0 + 1;
            const float vx0 = (x0 >= 0 && x0 < WIM) ? 1.f : 0.f;
            const float vx1 = (x1 >= 0 && x1 < WIM) ? 1.f : 0.f;
            const float vy0 = (y0 >= 0 && y0 < HIM) ? 1.f : 0.f;
            const float vy1 = (y1 >= 0 && y1 < HIM) ? 1.f : 0.f;
            const int cx0 = min(max(x0, 0), WIM-1), cx1 = min(max(x1, 0), WIM-1);
            const int cy0 = min(max(y0, 0), HIM-1), cy1 = min(max(y1, 0), HIM-1);
            const float w00 = (1.0f-fx)*(1.0f-fy)*vx0*vy0;
            const float w01 = fx*(1.0f-fy)*vx1*vy0;
            const float w10 = (1.0f-fx)*fy*vx0*vy1;
            const float w11 = fx*fy*vx1*vy1;
            const float* img = images + (size_t)n*3*HIM*WIM;
            #pragma unroll
            for (int ch = 0; ch < 3; ++ch) {
                const float* b = img + ch*HIM*WIM;
                const float p00 = b[cy0*WIM + cx0]*0.5f + 0.5f;   // feats = img*0.5+0.5
                const float p01 = b[cy0*WIM + cx1]*0.5f + 0.5f;
                const float p10 = b[cy1*WIM + cx0]*0.5f + 0.5f;
                const float p11 = b[cy1*WIM + cx1]*0.5f + 0.5f;
                const float lv  = p00*w00 + p01*w01 + p10*w10 + p11*w11;
                if (ch == 0) l0 = lv; else if (ch == 1) l1 = lv; else l2 = lv;
            }
        }

        // out_latent[n][c][p] — streaming, never re-read: non-temporal
        __builtin_nontemporal_store(l0, out_latent + (size_t)n*3*NPTS + 0*NPTS + p);
        __builtin_nontemporal_store(l1, out_latent + (size_t)n*3*NPTS + 1*NPTS + p);
        __builtin_nontemporal_store(l2, out_latent + (size_t)n*3*NPTS + 2*NPTS + p);

        // MLP: 9 -> relu 3 -> relu 3 -> 3
        float xin[9] = {l0, l1, l2, camx, camy, camz, d0, d1, d2};
        float h1[3], h2[3], h3[3];
        #pragma unroll
        for (int k = 0; k < 3; ++k) {
            float s = 0.f;
            #pragma unroll
            for (int j = 0; j < 9; ++j) s += xin[j] * dw1[k*9 + j];
            s += db1[k];
            h1[k] = fmaxf(s, 0.f);
        }
        #pragma unroll
        for (int k = 0; k < 3; ++k) {
            float s = 0.f;
            #pragma unroll
            for (int j = 0; j < 3; ++j) s += h1[j] * dw2[k*3 + j];
            s += db2[k];
            h2[k] = fmaxf(s, 0.f);
        }
        #pragma unroll
        for (int k = 0; k < 3; ++k) {
            float s = 0.f;
            #pragma unroll
            for (int j = 0; j < 3; ++j) s += h2[j] * dw3[k*3 + j];
            s += db3[k];
            h3[k] = s;
        }

        // lat5[n][p][c] — streaming: non-temporal
        float* lp = lat5 + ((size_t)n*NPTS + p)*3;
        __builtin_nontemporal_store(h3[0], lp + 0);
        __builtin_nontemporal_store(h3[1], lp + 1);
        __builtin_nontemporal_store(h3[2], lp + 2);
        a0 += h3[0]; a1 += h3[1]; a2 += h3[2];
    }

    if (write_latm) {
        latm[0*NPTS + p] = a0 * 0.125f;
        latm[1*NPTS + p] = a1 * 0.125f;
        latm[2*NPTS + p] = a2 * 0.125f;
    }
}

// Kernel 2: one wave per softmax line. dir = blockIdx.y:
//   0: softmax over X (w_yz) -> fl_yz -> scene_yz
//   1: softmax over Y (w_xz) -> fl_xz -> scene_xz
//   2: softmax over Z (w_xy) -> fl_xy -> scene_xy
__global__ __launch_bounds__(64)
void k2_agg(const float* __restrict__ latm, const float* __restrict__ lat5, int use_ws,
            const float* __restrict__ yzw1, const float* __restrict__ yzb1,
            const float* __restrict__ yzw2, const float* __restrict__ yzb2,
            const float* __restrict__ xzw1, const float* __restrict__ xzb1,
            const float* __restrict__ xzw2, const float* __restrict__ xzb2,
            const float* __restrict__ xyw1, const float* __restrict__ xyb1,
            const float* __restrict__ xyw2, const float* __restrict__ xyb2,
            float* __restrict__ out)
{
    const int dir = blockIdx.y;
    const int l   = blockIdx.x;       // line id in [0, 9216)
    const int t   = threadIdx.x;      // 64 lanes
    const int la  = l / GSZ;          // (y | x | x)
    const int lb  = l - la * GSZ;     // (z | z | y)

    const float* w1 = (dir == 0) ? yzw1 : (dir == 1) ? xzw1 : xyw1;
    const float* b1 = (dir == 0) ? yzb1 : (dir == 1) ? xzb1 : xyb1;
    const float* w2 = (dir == 0) ? yzw2 : (dir == 1) ? xzw2 : xyw2;
    const float* b2 = (dir == 0) ? yzb2 : (dir == 1) ? xzb2 : xyb2;

    auto eval = [&](int vi, float& s, float& v0, float& v1, float& v2) {
        int p;
        float coord;
        if (dir == 0)      { p = vi*GS2 + la*GSZ + lb; coord = (float)vi*(2.0f/95.0f) - 1.0f; }
        else if (dir == 1) { p = la*GS2 + vi*GSZ + lb; coord = (float)vi*(2.0f/95.0f) - 1.0f; }
        else               { p = la*GS2 + lb*GSZ + vi; coord = (float)vi*(1.0f/95.0f); }
        if (use_ws) {
            v0 = latm[p]; v1 = latm[NPTS + p]; v2 = latm[2*NPTS + p];
        } else {
            v0 = 0.f; v1 = 0.f; v2 = 0.f;
            for (int n = 0; n < NVIEW; ++n) {
                const float* q = lat5 + ((size_t)n*NPTS + p)*3;
                v0 += q[0]; v1 += q[1]; v2 += q[2];
            }
            v0 *= 0.125f; v1 *= 0.125f; v2 *= 0.125f;
        }
        float h[3];
        #pragma unroll
        for (int k = 0; k < 3; ++k) {
            float a = v0*w1[k*4+0] + v1*w1[k*4+1] + v2*w1[k*4+2] + coord*w1[k*4+3] + b1[k];
            h[k] = fmaxf(a, 0.f);
        }
        s = h[0]*w2[0] + h[1]*w2[1] + h[2]*w2[2] + b2[0];
    };

    float s0, va0, va1, va2;
    eval(t, s0, va0, va1, va2);
    const bool hasB = (t < GSZ - 64);   // lanes 0..31 handle voxel t+64
    float s1 = -__builtin_inff(), vb0 = 0.f, vb1 = 0.f, vb2 = 0.f;
    if (hasB) eval(t + 64, s1, vb0, vb1, vb2);

    float m = red_max64(fmaxf(s0, s1));
    const float e0 = expf(s0 - m);
    const float e1 = hasB ? expf(s1 - m) : 0.f;

    float den = red_sum64(e0 + e1);
    float n0  = red_sum64(e0*va0 + e1*vb0);
    float n1  = red_sum64(e0*va1 + e1*vb1);
    float n2  = red_sum64(e0*va2 + e1*vb2);

    if (t == 0) {
        // scene_xz at 0, scene_xy at 27648, scene_yz at 55296
        float* base = out + ((dir == 0) ? 2*SCENE_SZ : (dir == 1) ? 0 : SCENE_SZ);
        base[0*GS2 + la*GSZ + lb] = n0 / den;
        base[1*GS2 + la*GSZ + lb] = n1 / den;
        base[2*GS2 + la*GSZ + lb] = n2 / den;
    }
}

extern "C" void kernel_launch(void* const* d_in, const int* in_sizes, int n_in,
                              void* d_out, int out_size, void* d_ws, size_t ws_size,
                              hipStream_t stream) {
    const float* images = (const float*)d_in[0];
    const float* poses  = (const float*)d_in[1];
    const float* focal  = (const float*)d_in[2];
    const float* cc     = (const float*)d_in[3];
    const float* dw1 = (const float*)d_in[4];  const float* db1 = (const float*)d_in[5];
    const float* dw2 = (const float*)d_in[6];  const float* db2 = (const float*)d_in[7];
    const float* dw3 = (const float*)d_in[8];  const float* db3 = (const float*)d_in[9];
    const float* yzw1 = (const float*)d_in[10]; const float* yzb1 = (const float*)d_in[11];
    const float* yzw2 = (const float*)d_in[12]; const float* yzb2 = (const float*)d_in[13];
    const float* xzw1 = (const float*)d_in[14]; const float* xzb1 = (const float*)d_in[15];
    const float* xzw2 = (const float*)d_in[16]; const float* xzb2 = (const float*)d_in[17];
    const float* xyw1 = (const float*)d_in[18]; const float* xyb1 = (const float*)d_in[19];
    const float* xyw2 = (const float*)d_in[20]; const float* xyb2 = (const float*)d_in[21];

    float* out        = (float*)d_out;
    float* out_latent = out + OUTLAT_OFF;
    float* lat5       = out + LAT5_OFF;
    float* latm       = (float*)d_ws;
    const int use_ws  = (d_ws != nullptr &&
                         ws_size >= (size_t)NPTS * 3 * sizeof(float)) ? 1 : 0;

    hipLaunchKernelGGL(k1_sample_mlp, dim3(NPTS/256), dim3(256), 0, stream,
                       images, poses, focal, cc, dw1, db1, dw2, db2, dw3, db3,
                       out_latent, lat5, latm, use_ws);
    hipLaunchKernelGGL(k2_agg, dim3(GS2, 3), dim3(64), 0, stream,
                       latm, lat5, use_ws,
                       yzw1, yzb1, yzw2, yzb2,
                       xzw1, xzb1, xzw2, xzb2,
                       xyw1, xyb1, xyw2, xyb2,
                       out);
}

// Round 17
// 308.813 us; speedup vs baseline: 1.2500x; 1.2500x over previous
//
#include <hip/hip_runtime.h>
#include <math.h>

#define GSZ  96
#define GS2  (GSZ*GSZ)            // 9216
#define NPTS (GSZ*GSZ*GSZ)        // 884736
#define NVIEW 8
#define HIM  256
#define WIM  256
#define NPIX (HIM*WIM)            // 65536

#define SCENE_SZ   (3*GS2)        // 27648
#define OUTLAT_OFF (3*SCENE_SZ)   // 82944
#define LAT5_OFF   (OUTLAT_OFF + NVIEW*3*NPTS)  // 82944 + 21233664

#define LATM_BYTES ((size_t)3*NPTS*sizeof(float))        // 10,616,832
#define IMG4_BYTES ((size_t)NVIEW*NPIX*sizeof(float4))   //  8,388,608

__device__ __forceinline__ float red_max64(float v) {
    #pragma unroll
    for (int m = 32; m >= 1; m >>= 1) v = fmaxf(v, __shfl_xor(v, m, 64));
    return v;
}
__device__ __forceinline__ float red_sum64(float v) {
    #pragma unroll
    for (int m = 32; m >= 1; m >>= 1) v += __shfl_xor(v, m, 64);
    return v;
}

// Kernel 0: interleave images into [n][pix] float4 (feats = img*0.5+0.5 folded in).
__global__ __launch_bounds__(256)
void k0_interleave(const float* __restrict__ images, float4* __restrict__ img4)
{
    const int g   = blockIdx.x * 256 + threadIdx.x;   // 0 .. NVIEW*NPIX-1
    const int n   = g >> 16;
    const int pix = g & (NPIX - 1);
    const float* base = images + (size_t)n * 3 * NPIX + pix;
    float4 v;
    v.x = base[0]        * 0.5f + 0.5f;
    v.y = base[NPIX]     * 0.5f + 0.5f;
    v.z = base[2*NPIX]   * 0.5f + 0.5f;
    v.w = 0.f;
    img4[g] = v;
}

// Kernel 1: 16x16 (iy,iz) tile per block; wave footprint 4x16 -> compact image patch.
__global__ __launch_bounds__(256)
void k1_sample_mlp(const float* __restrict__ images, const float4* __restrict__ img4,
                   int use_img4,
                   const float* __restrict__ poses,
                   const float* __restrict__ focal, const float* __restrict__ cc,
                   const float* __restrict__ dw1, const float* __restrict__ db1,
                   const float* __restrict__ dw2, const float* __restrict__ db2,
                   const float* __restrict__ dw3, const float* __restrict__ db3,
                   float* __restrict__ out_latent, float* __restrict__ lat5,
                   float* __restrict__ latm, int write_latm)
{
    const int ty = threadIdx.x >> 4;            // 0..15
    const int tz = threadIdx.x & 15;            // 0..15
    const int iy = blockIdx.x * 16 + ty;
    const int iz = blockIdx.y * 16 + tz;
    const int ix = blockIdx.z;
    const int p  = ix * GS2 + iy * GSZ + iz;

    // world grid: xs,ys = linspace(-1,1,96); zs = linspace(0,1,96)
    const float wxv = (float)ix * (2.0f/95.0f) - 1.0f;
    const float wyv = (float)iy * (2.0f/95.0f) - 1.0f;
    const float wzv = (float)iz * (1.0f/95.0f);

    const float f   = focal[0] * 0.5f;   // focal / stride, stride = 2
    const float c2x = cc[0] * 0.5f;
    const float c2y = cc[1] * 0.5f;

    float a0 = 0.f, a1 = 0.f, a2 = 0.f;

    for (int n = 0; n < NVIEW; ++n) {
        const float* ps = poses + n * 16;
        const float r00 = ps[0], r01 = ps[1], r02 = ps[2],  tx = ps[3];
        const float r10 = ps[4], r11 = ps[5], r12 = ps[6],  tyy = ps[7];
        const float r20 = ps[8], r21 = ps[9], r22 = ps[10], tzz = ps[11];

        const float dx = wxv - tx, dy = wyv - tyy, dz = wzv - tzz;
        const float camx = dx*r00 + dy*r10 + dz*r20;
        const float camy = dx*r01 + dy*r11 + dz*r21;
        const float camz = dx*r02 + dy*r12 + dz*r22;

        const float ex = dx + 1e-9f, ey = dy + 1e-9f, ez = dz + 1e-9f;
        const float dn = sqrtf(ex*ex + ey*ey + ez*ez);
        const bool  mz = camz < 0.001f;
        float d0 = 0.f, d1 = 0.f, d2 = 0.f;
        if (mz) { d0 = dx/dn; d1 = dy/dn; d2 = dz/dn; }

        const float u = camx/camz * f    + c2x;
        const float v = camy/camz * (-f) + c2y;
        const float gxn = 2.0f*u/127.0f - 1.0f;   // W_feat-1 = 127
        const float gyn = 2.0f*v/127.0f - 1.0f;

        float l0 = 0.f, l1 = 0.f, l2 = 0.f;
        const bool inside = (fabsf(gxn) <= 1.0f) && (fabsf(gyn) <= 1.0f) && mz;
        if (inside) {
            const float sx = (gxn + 1.0f) * 255.0f * 0.5f;
            const float sy = (gyn + 1.0f) * 255.0f * 0.5f;
            const float x0f = floorf(sx), y0f = floorf(sy);
            const float fx = sx - x0f, fy = sy - y0f;
            const int x0 = (int)x0f, y0 = (int)y0f;
            const int x1 = x0 + 1,  y1 = y0 + 1;
            const float vx0 = (x0 >= 0 && x0 < WIM) ? 1.f : 0.f;
            const float vx1 = (x1 >= 0 && x1 < WIM) ? 1.f : 0.f;
            const float vy0 = (y0 >= 0 && y0 < HIM) ? 1.f : 0.f;
            const float vy1 = (y1 >= 0 && y1 < HIM) ? 1.f : 0.f;
            const int cx0 = min(max(x0, 0), WIM-1), cx1 = min(max(x1, 0), WIM-1);
            const int cy0 = min(max(y0, 0), HIM-1), cy1 = min(max(y1, 0), HIM-1);
            const float w00 = (1.0f-fx)*(1.0f-fy)*vx0*vy0;
            const float w01 = fx*(1.0f-fy)*vx1*vy0;
            const float w10 = (1.0f-fx)*fy*vx0*vy1;
            const float w11 = fx*fy*vx1*vy1;
            if (use_img4) {
                const float4* iv = img4 + (size_t)n * NPIX;
                const float4 q00 = iv[cy0*WIM + cx0];
                const float4 q01 = iv[cy0*WIM + cx1];
                const float4 q10 = iv[cy1*WIM + cx0];
                const float4 q11 = iv[cy1*WIM + cx1];
                l0 = q00.x*w00 + q01.x*w01 + q10.x*w10 + q11.x*w11;
                l1 = q00.y*w00 + q01.y*w01 + q10.y*w10 + q11.y*w11;
                l2 = q00.z*w00 + q01.z*w01 + q10.z*w10 + q11.z*w11;
            } else {
                const float* img = images + (size_t)n*3*NPIX;
                #pragma unroll
                for (int ch = 0; ch < 3; ++ch) {
                    const float* b = img + ch*NPIX;
                    const float p00 = b[cy0*WIM + cx0]*0.5f + 0.5f;
                    const float p01 = b[cy0*WIM + cx1]*0.5f + 0.5f;
                    const float p10 = b[cy1*WIM + cx0]*0.5f + 0.5f;
                    const float p11 = b[cy1*WIM + cx1]*0.5f + 0.5f;
                    const float lv  = p00*w00 + p01*w01 + p10*w10 + p11*w11;
                    if (ch == 0) l0 = lv; else if (ch == 1) l1 = lv; else l2 = lv;
                }
            }
        }

        // out_latent[n][c][p] — streaming, never re-read: non-temporal
        __builtin_nontemporal_store(l0, out_latent + (size_t)n*3*NPTS + 0*NPTS + p);
        __builtin_nontemporal_store(l1, out_latent + (size_t)n*3*NPTS + 1*NPTS + p);
        __builtin_nontemporal_store(l2, out_latent + (size_t)n*3*NPTS + 2*NPTS + p);

        // MLP: 9 -> relu 3 -> relu 3 -> 3
        float xin[9] = {l0, l1, l2, camx, camy, camz, d0, d1, d2};
        float h1[3], h2[3], h3[3];
        #pragma unroll
        for (int k = 0; k < 3; ++k) {
            float s = 0.f;
            #pragma unroll
            for (int j = 0; j < 9; ++j) s += xin[j] * dw1[k*9 + j];
            h1[k] = fmaxf(s + db1[k], 0.f);
        }
        #pragma unroll
        for (int k = 0; k < 3; ++k) {
            float s = 0.f;
            #pragma unroll
            for (int j = 0; j < 3; ++j) s += h1[j] * dw2[k*3 + j];
            h2[k] = fmaxf(s + db2[k], 0.f);
        }
        #pragma unroll
        for (int k = 0; k < 3; ++k) {
            float s = 0.f;
            #pragma unroll
            for (int j = 0; j < 3; ++j) s += h2[j] * dw3[k*3 + j];
            h3[k] = s + db3[k];
        }

        float* lp = lat5 + ((size_t)n*NPTS + p)*3;
        __builtin_nontemporal_store(h3[0], lp + 0);
        __builtin_nontemporal_store(h3[1], lp + 1);
        __builtin_nontemporal_store(h3[2], lp + 2);
        a0 += h3[0]; a1 += h3[1]; a2 += h3[2];
    }

    if (write_latm) {
        latm[0*NPTS + p] = a0 * 0.125f;
        latm[1*NPTS + p] = a1 * 0.125f;
        latm[2*NPTS + p] = a2 * 0.125f;
    }
}

// Kernel 2a: dirs 0 (softmax over x -> scene_yz) and 1 (softmax over y -> scene_xz).
// One THREAD per output line; loop over the softmax axis with online softmax.
// Lanes = consecutive line ids -> coalesced latm reads and output stores.
__global__ __launch_bounds__(256)
void k2a_lines(const float* __restrict__ latm, const float* __restrict__ lat5, int use_ws,
               const float* __restrict__ yzw1, const float* __restrict__ yzb1,
               const float* __restrict__ yzw2, const float* __restrict__ yzb2,
               const float* __restrict__ xzw1, const float* __restrict__ xzb1,
               const float* __restrict__ xzw2, const float* __restrict__ xzb2,
               float* __restrict__ out)
{
    const int dir = blockIdx.y;                       // 0 or 1
    const int t   = blockIdx.x * 256 + threadIdx.x;   // line id 0..9215
    const int la  = t / GSZ;                          // (y | x)
    const int lb  = t - la * GSZ;                     // z

    const float* w1 = (dir == 0) ? yzw1 : xzw1;
    const float* b1 = (dir == 0) ? yzb1 : xzb1;
    const float* w2 = (dir == 0) ? yzw2 : xzw2;
    const float* b2 = (dir == 0) ? yzb2 : xzb2;
    float W1[12], B1[3], W2[3];
    #pragma unroll
    for (int k = 0; k < 12; ++k) W1[k] = w1[k];
    #pragma unroll
    for (int k = 0; k < 3;  ++k) { B1[k] = b1[k]; W2[k] = w2[k]; }
    const float B2 = b2[0];

    float m = -INFINITY, den = 0.f, q0 = 0.f, q1 = 0.f, q2 = 0.f;
    for (int vi = 0; vi < GSZ; ++vi) {
        const int p = (dir == 0) ? (vi*GS2 + t) : (la*GS2 + vi*GSZ + lb);
        const float coord = (float)vi * (2.0f/95.0f) - 1.0f;
        float v0, v1, v2;
        if (use_ws) {
            v0 = latm[p]; v1 = latm[NPTS + p]; v2 = latm[2*NPTS + p];
        } else {
            v0 = 0.f; v1 = 0.f; v2 = 0.f;
            for (int n = 0; n < NVIEW; ++n) {
                const float* q = lat5 + ((size_t)n*NPTS + p)*3;
                v0 += q[0]; v1 += q[1]; v2 += q[2];
            }
            v0 *= 0.125f; v1 *= 0.125f; v2 *= 0.125f;
        }
        float h[3];
        #pragma unroll
        for (int k = 0; k < 3; ++k) {
            float a = v0*W1[k*4+0] + v1*W1[k*4+1] + v2*W1[k*4+2] + coord*W1[k*4+3] + B1[k];
            h[k] = fmaxf(a, 0.f);
        }
        const float s = h[0]*W2[0] + h[1]*W2[1] + h[2]*W2[2] + B2;
        // online softmax update
        const float mn = fmaxf(m, s);
        const float c  = expf(m - mn);     // exp(-inf)=0 on first iter
        const float e  = expf(s - mn);
        den = den*c + e;
        q0  = q0*c + e*v0;
        q1  = q1*c + e*v1;
        q2  = q2*c + e*v2;
        m = mn;
    }
    // dir0 -> scene_yz at 2*SCENE_SZ, index c*GS2 + y*96 + z = c*GS2 + t
    // dir1 -> scene_xz at 0,          index c*GS2 + x*96 + z = c*GS2 + t
    float* base = out + ((dir == 0) ? 2*SCENE_SZ : 0);
    base[0*GS2 + t] = q0 / den;
    base[1*GS2 + t] = q1 / den;
    base[2*GS2 + t] = q2 / den;
}

// Kernel 2b: dir 2 (softmax over z -> scene_xy). One WAVE per line, lane = vi
// (consecutive vi -> coalesced). 4 lines per 256-thread block.
__global__ __launch_bounds__(256)
void k2b_zlines(const float* __restrict__ latm, const float* __restrict__ lat5, int use_ws,
                const float* __restrict__ xyw1, const float* __restrict__ xyb1,
                const float* __restrict__ xyw2, const float* __restrict__ xyb2,
                float* __restrict__ out)
{
    const int wv = threadIdx.x >> 6;
    const int t  = threadIdx.x & 63;
    const int l  = blockIdx.x * 4 + wv;   // line id 0..9215
    const int la = l / GSZ;               // x
    const int lb = l - la * GSZ;          // y

    auto eval = [&](int vi, float& s, float& v0, float& v1, float& v2) {
        const int p = la*GS2 + lb*GSZ + vi;
        const float coord = (float)vi * (1.0f/95.0f);
        if (use_ws) {
            v0 = latm[p]; v1 = latm[NPTS + p]; v2 = latm[2*NPTS + p];
        } else {
            v0 = 0.f; v1 = 0.f; v2 = 0.f;
            for (int n = 0; n < NVIEW; ++n) {
                const float* q = lat5 + ((size_t)n*NPTS + p)*3;
                v0 += q[0]; v1 += q[1]; v2 += q[2];
            }
            v0 *= 0.125f; v1 *= 0.125f; v2 *= 0.125f;
        }
        float h[3];
        #pragma unroll
        for (int k = 0; k < 3; ++k) {
            float a = v0*xyw1[k*4+0] + v1*xyw1[k*4+1] + v2*xyw1[k*4+2] + coord*xyw1[k*4+3] + xyb1[k];
            h[k] = fmaxf(a, 0.f);
        }
        s = h[0]*xyw2[0] + h[1]*xyw2[1] + h[2]*xyw2[2] + xyb2[0];
    };

    float s0, va0, va1, va2;
    eval(t, s0, va0, va1, va2);
    const bool hasB = (t < GSZ - 64);
    float s1 = -INFINITY, vb0 = 0.f, vb1 = 0.f, vb2 = 0.f;
    if (hasB) eval(t + 64, s1, vb0, vb1, vb2);

    const float m  = red_max64(fmaxf(s0, s1));
    const float e0 = expf(s0 - m);
    const float e1 = hasB ? expf(s1 - m) : 0.f;

    const float den = red_sum64(e0 + e1);
    const float n0  = red_sum64(e0*va0 + e1*vb0);
    const float n1  = red_sum64(e0*va1 + e1*vb1);
    const float n2  = red_sum64(e0*va2 + e1*vb2);

    if (t == 0) {
        float* base = out + SCENE_SZ;   // scene_xy
        base[0*GS2 + la*GSZ + lb] = n0 / den;
        base[1*GS2 + la*GSZ + lb] = n1 / den;
        base[2*GS2 + la*GSZ + lb] = n2 / den;
    }
}

extern "C" void kernel_launch(void* const* d_in, const int* in_sizes, int n_in,
                              void* d_out, int out_size, void* d_ws, size_t ws_size,
                              hipStream_t stream) {
    const float* images = (const float*)d_in[0];
    const float* poses  = (const float*)d_in[1];
    const float* focal  = (const float*)d_in[2];
    const float* cc     = (const float*)d_in[3];
    const float* dw1 = (const float*)d_in[4];  const float* db1 = (const float*)d_in[5];
    const float* dw2 = (const float*)d_in[6];  const float* db2 = (const float*)d_in[7];
    const float* dw3 = (const float*)d_in[8];  const float* db3 = (const float*)d_in[9];
    const float* yzw1 = (const float*)d_in[10]; const float* yzb1 = (const float*)d_in[11];
    const float* yzw2 = (const float*)d_in[12]; const float* yzb2 = (const float*)d_in[13];
    const float* xzw1 = (const float*)d_in[14]; const float* xzb1 = (const float*)d_in[15];
    const float* xzw2 = (const float*)d_in[16]; const float* xzb2 = (const float*)d_in[17];
    const float* xyw1 = (const float*)d_in[18]; const float* xyb1 = (const float*)d_in[19];
    const float* xyw2 = (const float*)d_in[20]; const float* xyb2 = (const float*)d_in[21];

    float* out        = (float*)d_out;
    float* out_latent = out + OUTLAT_OFF;
    float* lat5       = out + LAT5_OFF;
    float* latm       = (float*)d_ws;
    float4* img4      = (float4*)((char*)d_ws + LATM_BYTES);

    const int use_ws   = (d_ws != nullptr && ws_size >= LATM_BYTES) ? 1 : 0;
    const int use_img4 = (d_ws != nullptr && ws_size >= LATM_BYTES + IMG4_BYTES) ? 1 : 0;

    if (use_img4) {
        hipLaunchKernelGGL(k0_interleave, dim3(NVIEW*NPIX/256), dim3(256), 0, stream,
                           images, img4);
    }
    hipLaunchKernelGGL(k1_sample_mlp, dim3(6, 6, 96), dim3(256), 0, stream,
                       images, img4, use_img4, poses, focal, cc,
                       dw1, db1, dw2, db2, dw3, db3,
                       out_latent, lat5, latm, use_ws);
    hipLaunchKernelGGL(k2a_lines, dim3(GS2/256, 2), dim3(256), 0, stream,
                       latm, lat5, use_ws,
                       yzw1, yzb1, yzw2, yzb2,
                       xzw1, xzb1, xzw2, xzb2,
                       out);
    hipLaunchKernelGGL(k2b_zlines, dim3(GS2/4), dim3(256), 0, stream,
                       latm, lat5, use_ws,
                       xyw1, xyb1, xyw2, xyb2,
                       out);
}